// Round 1
// baseline (126.316 us; speedup 1.0000x reference)
//
#include <hip/hip_runtime.h>

#define B_N 16
#define C_N 3
#define H_N 512
#define W_N 512
#define PLANES (B_N * C_N)            // 48
#define ROWS_PER_BLOCK 32
#define CHUNKS (H_N / ROWS_PER_BLOCK) // 16
#define SCALE (-1.0f / 8192.0f)       // -1/(B*H) == -1/(B*W), weights all 1
#define EPS_F 1e-12f

// Main pass: reads x and ref exactly once.
//  - Row terms: each wave handles whole rows (64 lanes x 8 floats = 512),
//    shuffle-reduces norms/dot, accumulates the row cosine term.
//  - Column partials: each lane owns 8 fixed columns (4*lane..+3, 256+4*lane..+3);
//    register-accumulated over rows, LDS-combined across the 4 waves, then
//    atomicAdd into colws[plane][col][3].
__global__ __launch_bounds__(256) void spl_main_kernel(
    const float* __restrict__ x, const float* __restrict__ r,
    float* __restrict__ out, float* __restrict__ colws) {
    const int p     = blockIdx.x / CHUNKS;
    const int chunk = blockIdx.x % CHUNKS;
    const int wave  = threadIdx.x >> 6;
    const int lane  = threadIdx.x & 63;

    const float* xp = x + (size_t)p * (H_N * W_N);
    const float* rp = r + (size_t)p * (H_N * W_N);

    float cxx[8] = {0, 0, 0, 0, 0, 0, 0, 0};
    float crr[8] = {0, 0, 0, 0, 0, 0, 0, 0};
    float cxr[8] = {0, 0, 0, 0, 0, 0, 0, 0};
    float rowacc = 0.0f;  // valid on lane 0

    const int r0 = chunk * ROWS_PER_BLOCK;
    for (int j = 0; j < ROWS_PER_BLOCK / 4; ++j) {
        const int row = r0 + wave + 4 * j;
        const float4* xr4 = (const float4*)(xp + (size_t)row * W_N);
        const float4* rr4 = (const float4*)(rp + (size_t)row * W_N);
        const float4 xa = xr4[lane];
        const float4 xb = xr4[lane + 64];
        const float4 ra = rr4[lane];
        const float4 rb = rr4[lane + 64];

        // column partial accumulation (lane-owned columns)
        cxx[0] += xa.x * xa.x; cxx[1] += xa.y * xa.y; cxx[2] += xa.z * xa.z; cxx[3] += xa.w * xa.w;
        cxx[4] += xb.x * xb.x; cxx[5] += xb.y * xb.y; cxx[6] += xb.z * xb.z; cxx[7] += xb.w * xb.w;
        crr[0] += ra.x * ra.x; crr[1] += ra.y * ra.y; crr[2] += ra.z * ra.z; crr[3] += ra.w * ra.w;
        crr[4] += rb.x * rb.x; crr[5] += rb.y * rb.y; crr[6] += rb.z * rb.z; crr[7] += rb.w * rb.w;
        cxr[0] += xa.x * ra.x; cxr[1] += xa.y * ra.y; cxr[2] += xa.z * ra.z; cxr[3] += xa.w * ra.w;
        cxr[4] += xb.x * rb.x; cxr[5] += xb.y * rb.y; cxr[6] += xb.z * rb.z; cxr[7] += xb.w * rb.w;

        // row sums for this row (reduce across the 64 lanes of this wave)
        float sxx = xa.x * xa.x + xa.y * xa.y + xa.z * xa.z + xa.w * xa.w
                  + xb.x * xb.x + xb.y * xb.y + xb.z * xb.z + xb.w * xb.w;
        float srr = ra.x * ra.x + ra.y * ra.y + ra.z * ra.z + ra.w * ra.w
                  + rb.x * rb.x + rb.y * rb.y + rb.z * rb.z + rb.w * rb.w;
        float sxr = xa.x * ra.x + xa.y * ra.y + xa.z * ra.z + xa.w * ra.w
                  + xb.x * rb.x + xb.y * rb.y + xb.z * rb.z + xb.w * rb.w;
        #pragma unroll
        for (int m = 32; m > 0; m >>= 1) {
            sxx += __shfl_down(sxx, m, 64);
            srr += __shfl_down(srr, m, 64);
            sxr += __shfl_down(sxr, m, 64);
        }
        if (lane == 0) {
            const float nx = fmaxf(sqrtf(sxx), EPS_F);
            const float nr = fmaxf(sqrtf(srr), EPS_F);
            rowacc += sxr / (nx * nr);
        }
    }

    // ---- combine column partials across the block's 4 waves via LDS ----
    __shared__ float smem[4][W_N * 3];  // 24 KiB
    #pragma unroll
    for (int k = 0; k < 4; ++k) {
        const int c0 = 4 * lane + k;
        const int c1 = c0 + 256;
        smem[wave][c0 * 3 + 0] = cxx[k];
        smem[wave][c0 * 3 + 1] = crr[k];
        smem[wave][c0 * 3 + 2] = cxr[k];
        smem[wave][c1 * 3 + 0] = cxx[4 + k];
        smem[wave][c1 * 3 + 1] = crr[4 + k];
        smem[wave][c1 * 3 + 2] = cxr[4 + k];
    }
    __shared__ float rowsums[4];
    if (lane == 0) rowsums[wave] = rowacc;
    __syncthreads();

    for (int e = threadIdx.x; e < W_N * 3; e += 256) {
        const float v = smem[0][e] + smem[1][e] + smem[2][e] + smem[3][e];
        atomicAdd(&colws[(size_t)p * (W_N * 3) + e], v);
    }
    if (threadIdx.x == 0) {
        const float t = rowsums[0] + rowsums[1] + rowsums[2] + rowsums[3];
        atomicAdd(out, SCALE * t);
    }
}

// Finish: per-column cosine terms from accumulated sums, reduce, add to out.
__global__ __launch_bounds__(256) void spl_cols_kernel(
    const float* __restrict__ colws, float* __restrict__ out) {
    const int idx = blockIdx.x * 256 + threadIdx.x;  // [0, PLANES*W)
    float term = 0.0f;
    if (idx < PLANES * W_N) {
        const float sxx = colws[idx * 3 + 0];
        const float srr = colws[idx * 3 + 1];
        const float sxr = colws[idx * 3 + 2];
        const float nx = fmaxf(sqrtf(sxx), EPS_F);
        const float nr = fmaxf(sqrtf(srr), EPS_F);
        term = sxr / (nx * nr);
    }
    #pragma unroll
    for (int m = 32; m > 0; m >>= 1) term += __shfl_down(term, m, 64);
    __shared__ float ws[4];
    const int lane = threadIdx.x & 63, wave = threadIdx.x >> 6;
    if (lane == 0) ws[wave] = term;
    __syncthreads();
    if (threadIdx.x == 0)
        atomicAdd(out, SCALE * (ws[0] + ws[1] + ws[2] + ws[3]));
}

extern "C" void kernel_launch(void* const* d_in, const int* in_sizes, int n_in,
                              void* d_out, int out_size, void* d_ws, size_t ws_size,
                              hipStream_t stream) {
    const float* x   = (const float*)d_in[0];
    const float* ref = (const float*)d_in[1];
    float* out   = (float*)d_out;
    float* colws = (float*)d_ws;  // PLANES * W * 3 floats = 294,912 B

    hipMemsetAsync(colws, 0, (size_t)PLANES * W_N * 3 * sizeof(float), stream);
    hipMemsetAsync(out, 0, sizeof(float), stream);
    spl_main_kernel<<<PLANES * CHUNKS, 256, 0, stream>>>(x, ref, out, colws);
    spl_cols_kernel<<<(PLANES * W_N) / 256, 256, 0, stream>>>(colws, out);
}

// Round 2
// 119.922 us; speedup vs baseline: 1.0533x; 1.0533x over previous
//
#include <hip/hip_runtime.h>

#define B_N 16
#define C_N 3
#define H_N 512
#define W_N 512
#define PLANES (B_N * C_N)            // 48
#define ROWS_PER_BLOCK 32
#define CHUNKS (H_N / ROWS_PER_BLOCK) // 16
#define NBLK (PLANES * CHUNKS)        // 768
#define STATS3 (W_N * 3)              // 1536
#define SCALE (-1.0f / 8192.0f)       // -1/(B*H) == -1/(B*W), weights all 1
#define EPS_F 1e-12f

// K1: single streaming pass, reads x and ref exactly once.
//  - Row terms: each wave owns whole rows (64 lanes x 8 floats = 512),
//    shuffle-reduces norms/dot, accumulates cosine term per row.
//  - Column partials: each lane owns 8 fixed columns, register-accumulated,
//    LDS-combined across the block's 4 waves, then PLAIN coalesced stores to
//    colpart[block][1536] (no atomics — deterministic, no contention tail).
__global__ __launch_bounds__(256) void spl_main_kernel(
    const float* __restrict__ x, const float* __restrict__ r,
    float* __restrict__ colpart, float* __restrict__ rowpart) {
    const int p     = blockIdx.x / CHUNKS;
    const int chunk = blockIdx.x % CHUNKS;
    const int wave  = threadIdx.x >> 6;
    const int lane  = threadIdx.x & 63;

    const float* xp = x + (size_t)p * (H_N * W_N);
    const float* rp = r + (size_t)p * (H_N * W_N);

    float cxx[8] = {0, 0, 0, 0, 0, 0, 0, 0};
    float crr[8] = {0, 0, 0, 0, 0, 0, 0, 0};
    float cxr[8] = {0, 0, 0, 0, 0, 0, 0, 0};
    float rowacc = 0.0f;  // valid on lane 0

    const int r0 = chunk * ROWS_PER_BLOCK;
    for (int j = 0; j < ROWS_PER_BLOCK / 4; ++j) {
        const int row = r0 + wave + 4 * j;
        const float4* xr4 = (const float4*)(xp + (size_t)row * W_N);
        const float4* rr4 = (const float4*)(rp + (size_t)row * W_N);
        const float4 xa = xr4[lane];
        const float4 xb = xr4[lane + 64];
        const float4 ra = rr4[lane];
        const float4 rb = rr4[lane + 64];

        cxx[0] += xa.x * xa.x; cxx[1] += xa.y * xa.y; cxx[2] += xa.z * xa.z; cxx[3] += xa.w * xa.w;
        cxx[4] += xb.x * xb.x; cxx[5] += xb.y * xb.y; cxx[6] += xb.z * xb.z; cxx[7] += xb.w * xb.w;
        crr[0] += ra.x * ra.x; crr[1] += ra.y * ra.y; crr[2] += ra.z * ra.z; crr[3] += ra.w * ra.w;
        crr[4] += rb.x * rb.x; crr[5] += rb.y * rb.y; crr[6] += rb.z * rb.z; crr[7] += rb.w * rb.w;
        cxr[0] += xa.x * ra.x; cxr[1] += xa.y * ra.y; cxr[2] += xa.z * ra.z; cxr[3] += xa.w * ra.w;
        cxr[4] += xb.x * rb.x; cxr[5] += xb.y * rb.y; cxr[6] += xb.z * rb.z; cxr[7] += xb.w * rb.w;

        float sxx = cxx[0] + cxx[1] + cxx[2] + cxx[3] + cxx[4] + cxx[5] + cxx[6] + cxx[7];
        float srr = crr[0] + crr[1] + crr[2] + crr[3] + crr[4] + crr[5] + crr[6] + crr[7];
        float sxr = cxr[0] + cxr[1] + cxr[2] + cxr[3] + cxr[4] + cxr[5] + cxr[6] + cxr[7];
        // subtract running totals? No — instead compute per-row sums directly:
        // (recompute from this row's products to keep accumulators independent)
        sxx = xa.x * xa.x + xa.y * xa.y + xa.z * xa.z + xa.w * xa.w
            + xb.x * xb.x + xb.y * xb.y + xb.z * xb.z + xb.w * xb.w;
        srr = ra.x * ra.x + ra.y * ra.y + ra.z * ra.z + ra.w * ra.w
            + rb.x * rb.x + rb.y * rb.y + rb.z * rb.z + rb.w * rb.w;
        sxr = xa.x * ra.x + xa.y * ra.y + xa.z * ra.z + xa.w * ra.w
            + xb.x * rb.x + xb.y * rb.y + xb.z * rb.z + xb.w * rb.w;
        #pragma unroll
        for (int m = 32; m > 0; m >>= 1) {
            sxx += __shfl_down(sxx, m, 64);
            srr += __shfl_down(srr, m, 64);
            sxr += __shfl_down(sxr, m, 64);
        }
        if (lane == 0) {
            const float nx = fmaxf(sqrtf(sxx), EPS_F);
            const float nr = fmaxf(sqrtf(srr), EPS_F);
            rowacc += sxr / (nx * nr);
        }
    }

    // combine column partials across the block's 4 waves via LDS
    __shared__ float smem[4][STATS3];  // 24 KiB
    #pragma unroll
    for (int k = 0; k < 4; ++k) {
        const int c0 = 4 * lane + k;
        const int c1 = c0 + 256;
        smem[wave][c0 * 3 + 0] = cxx[k];
        smem[wave][c0 * 3 + 1] = crr[k];
        smem[wave][c0 * 3 + 2] = cxr[k];
        smem[wave][c1 * 3 + 0] = cxx[4 + k];
        smem[wave][c1 * 3 + 1] = crr[4 + k];
        smem[wave][c1 * 3 + 2] = cxr[4 + k];
    }
    __shared__ float rowsums[4];
    if (lane == 0) rowsums[wave] = rowacc;
    __syncthreads();

    float* cp = colpart + (size_t)blockIdx.x * STATS3;
    #pragma unroll
    for (int k = 0; k < 6; ++k) {
        const int e = threadIdx.x + 256 * k;
        cp[e] = smem[0][e] + smem[1][e] + smem[2][e] + smem[3][e];
    }
    if (threadIdx.x == 0)
        rowpart[blockIdx.x] = rowsums[0] + rowsums[1] + rowsums[2] + rowsums[3];
}

// K2: one block per plane — reduce the 16 chunk partials, form the 512
// column cosine terms, add the 16 row partial sums, write planesum[p].
__global__ __launch_bounds__(256) void spl_reduce_kernel(
    const float* __restrict__ colpart, const float* __restrict__ rowpart,
    float* __restrict__ planesum) {
    const int p = blockIdx.x;
    float acc[6] = {0, 0, 0, 0, 0, 0};
    const float* base = colpart + (size_t)p * CHUNKS * STATS3;
    for (int c = 0; c < CHUNKS; ++c) {
        const float* bc = base + c * STATS3;
        #pragma unroll
        for (int k = 0; k < 6; ++k) acc[k] += bc[threadIdx.x + 256 * k];
    }
    __shared__ float sums[STATS3];
    #pragma unroll
    for (int k = 0; k < 6; ++k) sums[threadIdx.x + 256 * k] = acc[k];
    __syncthreads();

    float term = 0.0f;
    #pragma unroll
    for (int k = 0; k < 2; ++k) {
        const int col = threadIdx.x + 256 * k;
        const float sxx = sums[col * 3 + 0];
        const float srr = sums[col * 3 + 1];
        const float sxr = sums[col * 3 + 2];
        term += sxr / (fmaxf(sqrtf(sxx), EPS_F) * fmaxf(sqrtf(srr), EPS_F));
    }
    if (threadIdx.x < CHUNKS) term += rowpart[p * CHUNKS + threadIdx.x];

    #pragma unroll
    for (int m = 32; m > 0; m >>= 1) term += __shfl_down(term, m, 64);
    __shared__ float ws[4];
    if ((threadIdx.x & 63) == 0) ws[threadIdx.x >> 6] = term;
    __syncthreads();
    if (threadIdx.x == 0) planesum[p] = ws[0] + ws[1] + ws[2] + ws[3];
}

// K3: one wave folds the 48 plane scalars and writes the output directly.
__global__ void spl_final_kernel(const float* __restrict__ planesum,
                                 float* __restrict__ out) {
    float v = (threadIdx.x < PLANES) ? planesum[threadIdx.x] : 0.0f;
    #pragma unroll
    for (int m = 32; m > 0; m >>= 1) v += __shfl_down(v, m, 64);
    if (threadIdx.x == 0) out[0] = SCALE * v;
}

extern "C" void kernel_launch(void* const* d_in, const int* in_sizes, int n_in,
                              void* d_out, int out_size, void* d_ws, size_t ws_size,
                              hipStream_t stream) {
    const float* x   = (const float*)d_in[0];
    const float* ref = (const float*)d_in[1];
    float* out = (float*)d_out;

    float* colpart  = (float*)d_ws;                       // 768*1536 floats
    float* rowpart  = colpart + (size_t)NBLK * STATS3;    // 768 floats
    float* planesum = rowpart + NBLK;                     // 48 floats

    spl_main_kernel<<<NBLK, 256, 0, stream>>>(x, ref, colpart, rowpart);
    spl_reduce_kernel<<<PLANES, 256, 0, stream>>>(colpart, rowpart, planesum);
    spl_final_kernel<<<1, 64, 0, stream>>>(planesum, out);
}